// Round 14
// baseline (582.394 us; speedup 1.0000x reference)
//
#include <hip/hip_runtime.h>
#include <hip/hip_bf16.h>
#include <math.h>

#define HEAD_DIM 128
#define NH 16
#define NKV 4
#define BB 4
#define TT 2048
#define DD 2048
#define ROWS (BB*TT)   // 8192

typedef unsigned short u16;
typedef unsigned int u32;
typedef __attribute__((ext_vector_type(8))) short short8;
typedef __attribute__((ext_vector_type(4))) float f32x4;
typedef __attribute__((ext_vector_type(16))) float f32x16;
typedef __attribute__((ext_vector_type(4))) unsigned short u16x4;

__device__ __forceinline__ float bf2f(u16 u) {
    union { unsigned int i; float f; } v; v.i = ((unsigned int)u) << 16; return v.f;
}
__device__ __forceinline__ u16 f2bf(float f) {
    union { float f; unsigned int i; } v; v.f = f;
    unsigned int r = v.i + 0x7FFFu + ((v.i >> 16) & 1u);   // round-to-nearest-even
    return (u16)(r >> 16);
}
__device__ __forceinline__ f32x4 mfma16(short8 a, short8 b, f32x4 c) {
    return __builtin_amdgcn_mfma_f32_16x16x32_bf16(a, b, c, 0, 0, 0);
}
__device__ __forceinline__ f32x16 mfma32(short8 a, short8 b, f32x16 c) {
    return __builtin_amdgcn_mfma_f32_32x32x16_bf16(a, b, c, 0, 0, 0);
}
__device__ __forceinline__ f32x16 zero16() {
    f32x16 z;
    #pragma unroll
    for (int i = 0; i < 16; ++i) z[i] = 0.f;
    return z;
}
// async global->LDS, 16B per lane; lds dest wave-uniform (HW adds lane*16)
__device__ __forceinline__ void gload_lds16(const u16* g, u16* l) {
    __builtin_amdgcn_global_load_lds(
        (const __attribute__((address_space(1))) unsigned int*)(const void*)g,
        (__attribute__((address_space(3))) unsigned int*)(void*)l, 16, 0, 0);
}

// ---------------------------------------------------------------------------
// fp32 -> bf16 cast
// ---------------------------------------------------------------------------
__global__ __launch_bounds__(256)
void cast_f2b(const float* __restrict__ in, u16* __restrict__ out, int n)
{
    int i = (blockIdx.x * 256 + threadIdx.x) * 4;
    if (i >= n) return;
    float4 v = *(const float4*)(in + i);
    u16x4 o;
    o.x = f2bf(v.x); o.y = f2bf(v.y); o.z = f2bf(v.z); o.w = f2bf(v.w);
    *(u16x4*)(out + i) = o;
}

// ---------------------------------------------------------------------------
// RoPE tables
// ---------------------------------------------------------------------------
__global__ __launch_bounds__(256)
void rope_table(float* __restrict__ cs, float* __restrict__ sn, float base)
{
    int idx = blockIdx.x * 256 + threadIdx.x;
    if (idx >= TT * 64) return;
    int t = idx >> 6;
    int d = idx & 63;
    float inv = powf(base, -(float)(2 * d) / 128.0f);
    float f = (float)t * inv;
    cs[idx] = cosf(f);
    sn[idx] = sinf(f);
}

// ---------------------------------------------------------------------------
// Fused per-head RMSNorm + rotary (+gain) with pre-scale folding.
// relayout=0: out row = in row. relayout=1: out row = (b*heads+h)*T + t.
// ---------------------------------------------------------------------------
__global__ __launch_bounds__(256)
void rmsrope_bf16(const u16* __restrict__ xin, u16* __restrict__ xout,
                  const float* __restrict__ cs, const float* __restrict__ sn,
                  const float* __restrict__ gain,
                  int heads, int use_gain, float pre, int relayout)
{
    int row  = blockIdx.x * 4 + (threadIdx.x >> 6);
    int lane = threadIdx.x & 63;
    int h = row % heads;
    int t = (row / heads) % TT;
    int b = row / (heads * TT);
    size_t base = (size_t)row * HEAD_DIM;

    float x1 = bf2f(xin[base + lane]);
    float x2 = bf2f(xin[base + 64 + lane]);
    float ss = x1 * x1 + x2 * x2;
    #pragma unroll
    for (int m = 1; m < 64; m <<= 1) ss += __shfl_xor(ss, m, 64);
    float r = 1.0f / sqrtf(ss * (1.0f / 128.0f) + 1.1920929e-7f);
    x1 *= r; x2 *= r;

    float c = cs[t * 64 + lane];
    float s = sn[t * 64 + lane];
    float o1 =  x1 * c + x2 * s;
    float o2 = -x1 * s + x2 * c;
    float g = use_gain ? gain[h] * pre : pre;
    o1 *= g; o2 *= g;

    size_t orow = relayout ? ((size_t)(b * heads + h) * TT + t) : (size_t)row;
    size_t obase = orow * HEAD_DIM;
    xout[obase + lane]      = f2bf(o1);
    xout[obase + 64 + lane] = f2bf(o2);
}

// ---------------------------------------------------------------------------
// V transpose+relayout: vbh [B,T,KVH,128] -> vt [B,KVH, T/64, 128, 64] (bf16)
// kt-tiled; per-32 key permutation (bits 2<->3), proven rounds 5-13.
// ---------------------------------------------------------------------------
__global__ __launch_bounds__(256)
void transpose_v(const u16* __restrict__ vbh, u16* __restrict__ vtb)
{
    __shared__ u16 tile[64][72];
    const int tb = blockIdx.x;
    const int db = blockIdx.y;
    const int z  = blockIdx.z;        // b*NKV + kvh
    const int tid = threadIdx.x;

    {
        const int r = tid >> 2, cq = tid & 3;
        const u16* src = vbh + ((size_t)(((z >> 2) * TT + tb * 64 + r) * NKV + (z & 3))) * 128
                             + db * 64 + cq * 16;
        short8 s0 = *(const short8*)(src);
        short8 s1 = *(const short8*)(src + 8);
        #pragma unroll
        for (int e = 0; e < 8; ++e) tile[r][cq * 16 + e]     = (u16)s0[e];
        #pragma unroll
        for (int e = 0; e < 8; ++e) tile[r][cq * 16 + 8 + e] = (u16)s1[e];
    }
    __syncthreads();
    {
        const int d = tid >> 2, tq = tid & 3;
        __attribute__((aligned(16))) u16 tmp[16];
        #pragma unroll
        for (int e = 0; e < 16; ++e) {
            int esw = (e & 3) | ((e & 4) << 1) | ((e & 8) >> 1);  // swap bits 2,3
            tmp[e] = tile[tq * 16 + esw][d];
        }
        u16* dst = vtb + (((size_t)(z * (TT / 64) + tb) * 128 + (db * 64 + d)) << 6) + tq * 16;
        *(short8*)(dst)     = ((short8*)tmp)[0];
        *(short8*)(dst + 8) = ((short8*)tmp)[1];
    }
}

// ---------------------------------------------------------------------------
// 256-tile GEMM, counted-vmcnt pipeline (round-10 proven).
// ---------------------------------------------------------------------------
template<int BN, int OUTMODE>
__global__ __launch_bounds__(512, 2)
void gemm256(const u16* __restrict__ A, const u16* __restrict__ W,
             void* __restrict__ C0, void* __restrict__ C1)
{
    constexpr int WN    = (BN == 256) ? 4 : 2;
    constexpr int MR    = (BN == 256) ? 8 : 4;
    constexpr int WROW  = (BN == 256) ? 128 : 64;
    constexpr int NT    = DD / 64;
    constexpr int BROWS = BN / 8;
    constexpr int NBI   = BROWS / 8;

    __shared__ u16 AsL[2 * 256 * 64];
    __shared__ u16 BsL[2 * BN * 64];

    const int tid = threadIdx.x;
    const int w = tid >> 6, l = tid & 63;
    const int lq = l & 15, lg = l >> 4;
    const int wmi = (WN == 4) ? (w >> 2) : (w >> 1);
    const int wni = w & (WN - 1);

    int bmi, bni;
    {
        const int bid = blockIdx.x;
        const int wg = (bid & 7) * 32 + (bid >> 3);
        const int st = wg >> 2, wi = wg & 3;
        const int sty = st >> 2, stx = st & 3;
        bmi = sty * 2 + (wi >> 1);
        bni = stx * 2 + (wi & 1);
    }
    const int bm = bmi * 256, bn = bni * BN;

    const int r8 = l >> 3;
    const int chs = (l & 7) ^ r8;
    const u16* Ag = A + (size_t)(bm + r8) * DD + chs * 8;
    const u16* Wg = W + (size_t)(bn + r8) * DD + chs * 8;

    f32x4 acc[MR][4];
    #pragma unroll
    for (int m = 0; m < MR; ++m)
        #pragma unroll
        for (int n = 0; n < 4; ++n) acc[m][n] = (f32x4){0.f, 0.f, 0.f, 0.f};

    auto stage = [&](int buf, int t) {
        const size_t ko = (size_t)t * 64;
        u16* Ad = AsL + buf * (256 * 64);
        u16* Bd = BsL + buf * (BN * 64);
        #pragma unroll
        for (int j = 0; j < 4; ++j) {
            int rb = w * 32 + j * 8;
            gload_lds16(Ag + (size_t)rb * DD + ko, Ad + rb * 64);
        }
        #pragma unroll
        for (int j = 0; j < NBI; ++j) {
            int rb = w * BROWS + j * 8;
            gload_lds16(Wg + (size_t)rb * DD + ko, Bd + rb * 64);
        }
    };

    stage(0, 0);
    stage(1, 1);
    if constexpr (BN == 256) asm volatile("s_waitcnt vmcnt(8)" ::: "memory");
    else                     asm volatile("s_waitcnt vmcnt(6)" ::: "memory");
    __builtin_amdgcn_s_barrier();
    __builtin_amdgcn_sched_barrier(0);

    const int swz = lq & 7;
    for (int t = 0; t < NT; ++t) {
        const int buf = t & 1;
        const u16* Ab = AsL + buf * (256 * 64);
        const u16* Bb = BsL + buf * (BN * 64);
        #pragma unroll
        for (int ks = 0; ks < 2; ++ks) {
            short8 af[MR], bf[4];
            #pragma unroll
            for (int m = 0; m < MR; ++m) {
                int arow = wmi * WROW + m * 16 + lq;
                af[m] = *(const short8*)(Ab + arow * 64 + (((ks * 4 + lg) ^ swz) << 3));
            }
            #pragma unroll
            for (int n = 0; n < 4; ++n) {
                int brow = wni * 64 + n * 16 + lq;
                bf[n] = *(const short8*)(Bb + brow * 64 + (((ks * 4 + lg) ^ swz) << 3));
            }
            __builtin_amdgcn_s_setprio(1);
            #pragma unroll
            for (int m = 0; m < MR; ++m)
                #pragma unroll
                for (int n = 0; n < 4; ++n)
                    acc[m][n] = mfma16(af[m], bf[n], acc[m][n]);
            __builtin_amdgcn_s_setprio(0);
        }

        if (t + 1 < NT) {
            __builtin_amdgcn_sched_barrier(0);
            __builtin_amdgcn_s_barrier();
            if (t + 2 < NT) {
                stage(buf, t + 2);
                if constexpr (BN == 256) asm volatile("s_waitcnt vmcnt(8)" ::: "memory");
                else                     asm volatile("s_waitcnt vmcnt(6)" ::: "memory");
            } else {
                asm volatile("s_waitcnt vmcnt(0)" ::: "memory");
            }
            __builtin_amdgcn_s_barrier();
            __builtin_amdgcn_sched_barrier(0);
        }
    }

    #pragma unroll
    for (int m = 0; m < MR; ++m) {
        int grow = bm + wmi * WROW + m * 16 + lg * 4;
        #pragma unroll
        for (int n = 0; n < 4; ++n) {
            int col = wni * 64 + n * 16 + lq;
            #pragma unroll
            for (int q = 0; q < 4; ++q) {
                float v = acc[m][n][q];
                if constexpr (OUTMODE == 0) {
                    ((u16*)C0)[(size_t)(grow + q) * 2048 + bn + col] = f2bf(v);
                } else if constexpr (OUTMODE == 2) {
                    ((float*)C0)[(size_t)(grow + q) * 2048 + bn + col] = v;
                } else {
                    int cg = bn + col;
                    if (cg < 512)
                        ((u16*)C0)[(size_t)(grow + q) * 512 + cg] = f2bf(v);
                    else
                        ((u16*)C1)[(size_t)(grow + q) * 512 + (cg - 512)] = f2bf(v);
                }
            }
        }
    }
}

// ---------------------------------------------------------------------------
// Causal attention, NO-LDS / NO-BARRIER variant.
// K/V streams are L2-resident (FETCH=24.6MB measured) -> read MFMA fragments
// DIRECTLY from global/L2. Removes: LDS staging, all barriers, all bank
// conflicts; unlocks 4 blocks/CU (16 waves, 4/SIMD) for TLP phase-spread.
// Grid 1024: block = one 128-row q-block of one (b,h). Waves independent.
// Per-CU balance: qslot map with m[q]+m[q+8]=15 so round-robin-co-resident
// quads {q,q+4,q+8,q+12} sum to a constant. XCD mapping: bid&7 = stream.
// Core math (swapped-operand 32x32, in-reg softmax, in-lane P frags via
// V key-permutation, defer-max, exp2 domain) proven rounds 5-13.
// ---------------------------------------------------------------------------
__global__ __launch_bounds__(256, 4)
void attn_mfma(const u16* __restrict__ qg,   // [B,NH,T,128] head-major, pre-scaled
               const u16* __restrict__ kg,   // [B,KVH,T,128]
               const u16* __restrict__ vtg,  // [B,KVH,T/64,128,64] key-permuted
               u16* __restrict__ yg)         // [B,T,NH,128]
{
    const int tid = threadIdx.x, wid = tid >> 6, l = tid & 63;
    const int lq = l & 31, hi = l >> 5, hi4 = hi << 2;

    // bid = xcd + 8*slot; slot = (qslot<<3) | (hh<<1) | gsub
    const int bid   = blockIdx.x;
    const int xcd   = bid & 7;
    const int slot  = bid >> 3;
    const int gsub  = slot & 1;
    const int hh    = (slot >> 1) & 3;
    const int qslot = slot >> 3;                     // 0..15
    const int qblk  = (qslot < 8) ? qslot : 23 - qslot;   // m[q]+m[q+8]=15
    const int g     = xcd + (gsub << 3);             // b*NKV + kvh
    const int b = g >> 2, kvh = g & 3;
    const int h = kvh * 4 + hh;

    const u16* kg_bh = kg + (((size_t)g * TT) << 7);
    const u16* vt_bh = vtg + (size_t)g * (TT / 64) * 8192;
    const u16* q_bh  = qg + (((size_t)(b * NH + h) * TT) << 7);

    const int qrow = qblk * 128 + wid * 32 + lq;
    const int diag = (qblk * 128 + wid * 32) >> 6;   // wave's last (masked) tile

    // ---- Q fragments (one-time, head-major coalesced) ----
    const u16* qptr = q_bh + ((size_t)qrow << 7) + hi * 8;
    short8 qf[8];
    #pragma unroll
    for (int s = 0; s < 8; ++s)
        qf[s] = *(const short8*)(qptr + s * 16);

    f32x16 accO[4];
    #pragma unroll
    for (int d = 0; d < 4; ++d) accO[d] = zero16();
    float m2 = -1e30f, lr = 0.f;

    for (int kt = 0; kt <= diag; ++kt) {
        // ---- S^T = K·Q (16 MFMA), K fragments direct from L2 ----
        const u16* kbase = kg_bh + (((size_t)(kt * 64)) << 7);
        f32x16 accS0 = zero16(), accS1 = zero16();
        __builtin_amdgcn_s_setprio(1);
        #pragma unroll
        for (int ss = 0; ss < 8; ++ss) {
            const int c = (2 * ss + hi) << 3;        // k-slice chunk (u16 units)
            short8 kf0 = *(const short8*)(kbase + (lq << 7) + c);
            accS0 = mfma32(kf0, qf[ss], accS0);
            short8 kf1 = *(const short8*)(kbase + ((32 + lq) << 7) + c);
            accS1 = mfma32(kf1, qf[ss], accS1);
        }
        __builtin_amdgcn_s_setprio(0);

        // ---- scores + causal mask (diag tile only) ----
        float p[32];
        if (kt == diag) {
            #pragma unroll
            for (int r = 0; r < 16; ++r) {
                int key0 = kt * 64 + (r & 3) + 8 * (r >> 2) + hi4;
                p[r]      = (key0      > qrow) ? -INFINITY : accS0[r];
                p[16 + r] = (key0 + 32 > qrow) ? -INFINITY : accS1[r];
            }
        } else {
            #pragma unroll
            for (int r = 0; r < 16; ++r) { p[r] = accS0[r]; p[16 + r] = accS1[r]; }
        }

        // ---- row max (in-register trees + one cross-half shfl) ----
        float t16[16];
        #pragma unroll
        for (int i = 0; i < 16; ++i) t16[i] = fmaxf(p[i], p[i + 16]);
        #pragma unroll
        for (int i = 0; i < 8; ++i) t16[i] = fmaxf(t16[i], t16[i + 8]);
        #pragma unroll
        for (int i = 0; i < 4; ++i) t16[i] = fmaxf(t16[i], t16[i + 4]);
        float pm = fmaxf(fmaxf(t16[0], t16[1]), fmaxf(t16[2], t16[3]));
        pm = fmaxf(pm, __shfl_xor(pm, 32, 64));

        // ---- defer-max ----
        float mn = m2;
        if (!__all(pm - m2 <= 8.0f)) {
            mn = fmaxf(m2, pm);
            float al = exp2f(m2 - mn);
            lr *= al;
            #pragma unroll
            for (int d = 0; d < 4; ++d) accO[d] *= al;
            m2 = mn;
        }

        // ---- exp2 + row sum ----
        #pragma unroll
        for (int r = 0; r < 32; ++r) p[r] = exp2f(p[r] - mn);
        #pragma unroll
        for (int i = 0; i < 16; ++i) t16[i] = p[i] + p[i + 16];
        #pragma unroll
        for (int i = 0; i < 8; ++i) t16[i] += t16[i + 8];
        #pragma unroll
        for (int i = 0; i < 4; ++i) t16[i] += t16[i + 4];
        float rs = (t16[0] + t16[1]) + (t16[2] + t16[3]);
        rs += __shfl_xor(rs, 32, 64);
        lr += rs;

        // ---- P -> bf16 B-fragments via packed cvt (RTNE) ----
        short8 pfrag[4];
        #pragma unroll
        for (int kb = 0; kb < 2; ++kb)
            #pragma unroll
            for (int c = 0; c < 2; ++c) {
                union { u32 u[4]; short8 s8; } f;
                #pragma unroll
                for (int j = 0; j < 4; ++j) {
                    __hip_bfloat162 hb = __float22bfloat162_rn(
                        make_float2(p[kb * 16 + 8 * c + 2 * j],
                                    p[kb * 16 + 8 * c + 2 * j + 1]));
                    f.u[j] = *reinterpret_cast<u32*>(&hb);
                }
                pfrag[kb * 2 + c] = f.s8;
            }

        // ---- O^T += V^T · P^T (16 MFMA), V fragments direct from L2 ----
        const u16* vbase = vt_bh + (size_t)kt * 8192;
        #pragma unroll
        for (int d = 0; d < 4; ++d) {
            const u16* vr8 = vbase + ((d * 32 + lq) << 6);
            short8 vf0 = *(const short8*)(vr8 + ((0 + hi) << 3));
            short8 vf1 = *(const short8*)(vr8 + ((2 + hi) << 3));
            short8 vf2 = *(const short8*)(vr8 + ((4 + hi) << 3));
            short8 vf3 = *(const short8*)(vr8 + ((6 + hi) << 3));
            __builtin_amdgcn_s_setprio(1);
            accO[d] = mfma32(vf0, pfrag[0], accO[d]);
            accO[d] = mfma32(vf1, pfrag[1], accO[d]);
            accO[d] = mfma32(vf2, pfrag[2], accO[d]);
            accO[d] = mfma32(vf3, pfrag[3], accO[d]);
            __builtin_amdgcn_s_setprio(0);
        }
    }

    // ---- epilogue: normalize (lr lane-uniform) and store ----
    float inv = 1.0f / lr;
    u16* yrow = yg + ((size_t)((b * TT + qrow) * NH + h) << 7);
    #pragma unroll
    for (int d = 0; d < 4; ++d)
        #pragma unroll
        for (int r = 0; r < 4; ++r) {
            u16x4 o;
            #pragma unroll
            for (int q = 0; q < 4; ++q) o[q] = f2bf(accO[d][4 * r + q] * inv);
            *(u16x4*)(yrow + d * 32 + 8 * r + hi4) = o;
        }
}

// ---------------------------------------------------------------------------
extern "C" void kernel_launch(void* const* d_in, const int* in_sizes, int n_in,
                              void* d_out, int out_size, void* d_ws, size_t ws_size,
                              hipStream_t stream)
{
    const float* x      = (const float*)d_in[0];
    const float* q_w    = (const float*)d_in[1];
    const float* k_w    = (const float*)d_in[2];
    const float* v_w    = (const float*)d_in[3];
    const float* out_w  = (const float*)d_in[4];
    const float* q_gain = (const float*)d_in[5];
    float* out = (float*)d_out;

    char* ws = (char*)d_ws;
    u16* qh   = (u16*)(ws);                       // [0,32M)   proj-Q; later y
    u16* xh   = (u16*)(ws + 33554432ull);         // [32,64M)  x bf16; later q2
    u16* wqkv = (u16*)(ws + 67108864ull);         // [64,76.6M) wq+wkv; later kk
    u16* kh   = (u16*)(ws + 79691776ull);         // [76.6..84.6M) K proj; later vtb
    u16* vbh  = (u16*)(ws + 88080384ull);         // [84.6..92.6M) V proj; later wout
    float* cs = (float*)(ws + 96468992ull);       // 0.5MB
    float* sn = cs + TT * 64;                     // 0.5MB (total 97,517,568)
    u16* wq   = wqkv;                             // 8MB  [2048,2048]
    u16* wkv  = wqkv + 4194304;                   // 4MB  [1024,2048] = [k_w; v_w]
    u16* q2   = xh;                               // [B,NH,T,128]
    u16* kk   = wqkv;                             // [B,KVH,T,128]
    u16* vtb  = kh;                               // [B,KVH,T/64,128,64]
    u16* wout = vbh;                              // out-proj weights bf16
    u16* y    = qh;                               // attn output

    dim3 blk(256);

    // rope tables (T=2048 > train 1024 -> NTK base scaling)
    double base = 10000.0 * pow((double)TT / 1024.0, 128.0 / 126.0);
    rope_table<<<(TT * 64) / 256, blk, 0, stream>>>(cs, sn, (float)base);

    // casts: activations + weights
    cast_f2b<<<(ROWS * DD) / 1024, blk, 0, stream>>>(x, xh, ROWS * DD);
    cast_f2b<<<(DD * DD) / 1024, blk, 0, stream>>>(q_w, wq, DD * DD);
    cast_f2b<<<(512 * DD) / 1024, blk, 0, stream>>>(k_w, wkv, 512 * DD);
    cast_f2b<<<(512 * DD) / 1024, blk, 0, stream>>>(v_w, wkv + 1048576, 512 * DD);

    // projections (counted-vmcnt 256-tile GEMMs; 256 blocks = 1/CU each)
    gemm256<256, 0><<<dim3(256), dim3(512), 0, stream>>>(xh, wq, qh, nullptr);
    gemm256<128, 1><<<dim3(256), dim3(512), 0, stream>>>(xh, wkv, kh, vbh);

    // fused rmsnorm + rope; Q -> head-major q2 (xh, x dead) with
    // gain*scale*log2e folded; K -> head-major kk (wqkv, weights dead)
    const float pre_q = 0.08838834764831845f * 1.4426950408889634f;
    rmsrope_bf16<<<(ROWS * NH) / 4, blk, 0, stream>>>(qh, q2, cs, sn, q_gain, NH, 1, pre_q, 1);
    rmsrope_bf16<<<(ROWS * NKV) / 4, blk, 0, stream>>>(kh, kk, cs, sn, nullptr, NKV, 0, 1.0f, 1);

    // V -> [B,KVH,T/64,128,64] (vtb aliases kh; kh dead after rmsropeK)
    transpose_v<<<dim3(TT / 64, 2, BB * NKV), blk, 0, stream>>>(vbh, vtb);

    // out-proj weights (wout aliases vbh; vbh dead after transpose_v)
    cast_f2b<<<(DD * DD) / 1024, blk, 0, stream>>>(out_w, wout, DD * DD);

    // attention -> y (qh region; proj-Q dead after rmsrope). Grid 1024,
    // no LDS/barriers, 4 blocks/CU.
    attn_mfma<<<dim3(1024), blk, 0, stream>>>(q2, kk, vtb, y);

    // output projection (fp32 out)
    gemm256<256, 2><<<dim3(256), dim3(512), 0, stream>>>(y, wout, out, nullptr);
}

// Round 15
// 345.737 us; speedup vs baseline: 1.6845x; 1.6845x over previous
//
#include <hip/hip_runtime.h>
#include <hip/hip_bf16.h>
#include <math.h>

#define HEAD_DIM 128
#define NH 16
#define NKV 4
#define BB 4
#define TT 2048
#define DD 2048
#define ROWS (BB*TT)   // 8192

typedef unsigned short u16;
typedef unsigned int u32;
typedef __attribute__((ext_vector_type(8))) short short8;
typedef __attribute__((ext_vector_type(4))) float f32x4;
typedef __attribute__((ext_vector_type(16))) float f32x16;
typedef __attribute__((ext_vector_type(4))) unsigned short u16x4;

__device__ __forceinline__ float bf2f(u16 u) {
    union { unsigned int i; float f; } v; v.i = ((unsigned int)u) << 16; return v.f;
}
__device__ __forceinline__ u16 f2bf(float f) {
    union { float f; unsigned int i; } v; v.f = f;
    unsigned int r = v.i + 0x7FFFu + ((v.i >> 16) & 1u);   // round-to-nearest-even
    return (u16)(r >> 16);
}
__device__ __forceinline__ f32x4 mfma16(short8 a, short8 b, f32x4 c) {
    return __builtin_amdgcn_mfma_f32_16x16x32_bf16(a, b, c, 0, 0, 0);
}
__device__ __forceinline__ f32x16 mfma32(short8 a, short8 b, f32x16 c) {
    return __builtin_amdgcn_mfma_f32_32x32x16_bf16(a, b, c, 0, 0, 0);
}
__device__ __forceinline__ f32x16 zero16() {
    f32x16 z;
    #pragma unroll
    for (int i = 0; i < 16; ++i) z[i] = 0.f;
    return z;
}
// async global->LDS, 16B per lane; lds dest wave-uniform (HW adds lane*16)
__device__ __forceinline__ void gload_lds16(const u16* g, u16* l) {
    __builtin_amdgcn_global_load_lds(
        (const __attribute__((address_space(1))) unsigned int*)(const void*)g,
        (__attribute__((address_space(3))) unsigned int*)(void*)l, 16, 0, 0);
}

// ---------------------------------------------------------------------------
// fp32 -> bf16 cast (single-range)
// ---------------------------------------------------------------------------
__global__ __launch_bounds__(256)
void cast_f2b(const float* __restrict__ in, u16* __restrict__ out, int n)
{
    int i = (blockIdx.x * 256 + threadIdx.x) * 4;
    if (i >= n) return;
    float4 v = *(const float4*)(in + i);
    u16x4 o;
    o.x = f2bf(v.x); o.y = f2bf(v.y); o.z = f2bf(v.z); o.w = f2bf(v.w);
    *(u16x4*)(out + i) = o;
}

// ---------------------------------------------------------------------------
// prep_all: fused {x, q_w, k_w, v_w} casts + rope table build (5 launches -> 1)
// block segments: [0,16384) x; [16384,20480) q_w; [20480,21504) k_w;
// [21504,22528) v_w; [22528,23040) rope tables.
// ---------------------------------------------------------------------------
__global__ __launch_bounds__(256)
void prep_all(const float* __restrict__ x,  const float* __restrict__ qw,
              const float* __restrict__ kw, const float* __restrict__ vw,
              u16* __restrict__ xh, u16* __restrict__ wq, u16* __restrict__ wkv,
              float* __restrict__ cs, float* __restrict__ sn, float base)
{
    const int bid = blockIdx.x, tid = threadIdx.x;
    if (bid < 22528) {
        const float* src; u16* dst; int i4;
        if (bid < 16384)      { src = x;  dst = xh;            i4 = bid; }
        else if (bid < 20480) { src = qw; dst = wq;            i4 = bid - 16384; }
        else if (bid < 21504) { src = kw; dst = wkv;           i4 = bid - 20480; }
        else                  { src = vw; dst = wkv + 1048576; i4 = bid - 21504; }
        int i = (i4 * 256 + tid) * 4;
        float4 v = *(const float4*)(src + i);
        u16x4 o;
        o.x = f2bf(v.x); o.y = f2bf(v.y); o.z = f2bf(v.z); o.w = f2bf(v.w);
        *(u16x4*)(dst + i) = o;
    } else {
        int idx = (bid - 22528) * 256 + tid;     // < TT*64
        int t = idx >> 6;
        int d = idx & 63;
        float inv = powf(base, -(float)(2 * d) / 128.0f);
        float f = (float)t * inv;
        cs[idx] = cosf(f);
        sn[idx] = sinf(f);
    }
}

// ---------------------------------------------------------------------------
// Fused RMSNorm+RoPE for Q and K in one launch (head-major relayout).
// blocks [0,32768): Q rows (gain*pre folded); [32768,40960): K rows.
// ---------------------------------------------------------------------------
__global__ __launch_bounds__(256)
void rmsrope_qk(const u16* __restrict__ qin, u16* __restrict__ qout,
                const u16* __restrict__ kin, u16* __restrict__ kout,
                const float* __restrict__ cs, const float* __restrict__ sn,
                const float* __restrict__ gain, float pre)
{
    int row  = blockIdx.x * 4 + (threadIdx.x >> 6);
    int lane = threadIdx.x & 63;
    const u16* xin; u16* xout; int heads; int use_gain;
    if (row < 131072) { xin = qin; xout = qout; heads = NH;  use_gain = 1; }
    else { row -= 131072; xin = kin; xout = kout; heads = NKV; use_gain = 0; }

    int h = row % heads;
    int t = (row / heads) % TT;
    int b = row / (heads * TT);
    size_t base = (size_t)row * HEAD_DIM;

    float x1 = bf2f(xin[base + lane]);
    float x2 = bf2f(xin[base + 64 + lane]);
    float ss = x1 * x1 + x2 * x2;
    #pragma unroll
    for (int m = 1; m < 64; m <<= 1) ss += __shfl_xor(ss, m, 64);
    float r = 1.0f / sqrtf(ss * (1.0f / 128.0f) + 1.1920929e-7f);
    x1 *= r; x2 *= r;

    float c = cs[t * 64 + lane];
    float s = sn[t * 64 + lane];
    float o1 =  x1 * c + x2 * s;
    float o2 = -x1 * s + x2 * c;
    float g = use_gain ? gain[h] * pre : 1.0f;
    o1 *= g; o2 *= g;

    size_t obase = ((size_t)(b * heads + h) * TT + t) * HEAD_DIM;
    xout[obase + lane]      = f2bf(o1);
    xout[obase + 64 + lane] = f2bf(o2);
}

// ---------------------------------------------------------------------------
// V transpose+relayout: vbh [B,T,KVH,128] -> vt [B,KVH, T/64, 128, 64] (bf16)
// kt-tiled; per-32 key permutation (bits 2<->3), proven rounds 5-13.
// (NOT fused with rmsrope_qk: vtb aliases kh which rmsropeK reads.)
// ---------------------------------------------------------------------------
__global__ __launch_bounds__(256)
void transpose_v(const u16* __restrict__ vbh, u16* __restrict__ vtb)
{
    __shared__ u16 tile[64][72];
    const int tb = blockIdx.x;
    const int db = blockIdx.y;
    const int z  = blockIdx.z;        // b*NKV + kvh
    const int tid = threadIdx.x;

    {
        const int r = tid >> 2, cq = tid & 3;
        const u16* src = vbh + ((size_t)(((z >> 2) * TT + tb * 64 + r) * NKV + (z & 3))) * 128
                             + db * 64 + cq * 16;
        short8 s0 = *(const short8*)(src);
        short8 s1 = *(const short8*)(src + 8);
        #pragma unroll
        for (int e = 0; e < 8; ++e) tile[r][cq * 16 + e]     = (u16)s0[e];
        #pragma unroll
        for (int e = 0; e < 8; ++e) tile[r][cq * 16 + 8 + e] = (u16)s1[e];
    }
    __syncthreads();
    {
        const int d = tid >> 2, tq = tid & 3;
        __attribute__((aligned(16))) u16 tmp[16];
        #pragma unroll
        for (int e = 0; e < 16; ++e) {
            int esw = (e & 3) | ((e & 4) << 1) | ((e & 8) >> 1);  // swap bits 2,3
            tmp[e] = tile[tq * 16 + esw][d];
        }
        u16* dst = vtb + (((size_t)(z * (TT / 64) + tb) * 128 + (db * 64 + d)) << 6) + tq * 16;
        *(short8*)(dst)     = ((short8*)tmp)[0];
        *(short8*)(dst + 8) = ((short8*)tmp)[1];
    }
}

// ---------------------------------------------------------------------------
// 256-tile GEMM, counted-vmcnt pipeline (round-10 proven).
// ---------------------------------------------------------------------------
template<int BN, int OUTMODE>
__global__ __launch_bounds__(512, 2)
void gemm256(const u16* __restrict__ A, const u16* __restrict__ W,
             void* __restrict__ C0, void* __restrict__ C1)
{
    constexpr int WN    = (BN == 256) ? 4 : 2;
    constexpr int MR    = (BN == 256) ? 8 : 4;
    constexpr int WROW  = (BN == 256) ? 128 : 64;
    constexpr int NT    = DD / 64;
    constexpr int BROWS = BN / 8;
    constexpr int NBI   = BROWS / 8;

    __shared__ u16 AsL[2 * 256 * 64];
    __shared__ u16 BsL[2 * BN * 64];

    const int tid = threadIdx.x;
    const int w = tid >> 6, l = tid & 63;
    const int lq = l & 15, lg = l >> 4;
    const int wmi = (WN == 4) ? (w >> 2) : (w >> 1);
    const int wni = w & (WN - 1);

    int bmi, bni;
    {
        const int bid = blockIdx.x;
        const int wg = (bid & 7) * 32 + (bid >> 3);
        const int st = wg >> 2, wi = wg & 3;
        const int sty = st >> 2, stx = st & 3;
        bmi = sty * 2 + (wi >> 1);
        bni = stx * 2 + (wi & 1);
    }
    const int bm = bmi * 256, bn = bni * BN;

    const int r8 = l >> 3;
    const int chs = (l & 7) ^ r8;
    const u16* Ag = A + (size_t)(bm + r8) * DD + chs * 8;
    const u16* Wg = W + (size_t)(bn + r8) * DD + chs * 8;

    f32x4 acc[MR][4];
    #pragma unroll
    for (int m = 0; m < MR; ++m)
        #pragma unroll
        for (int n = 0; n < 4; ++n) acc[m][n] = (f32x4){0.f, 0.f, 0.f, 0.f};

    auto stage = [&](int buf, int t) {
        const size_t ko = (size_t)t * 64;
        u16* Ad = AsL + buf * (256 * 64);
        u16* Bd = BsL + buf * (BN * 64);
        #pragma unroll
        for (int j = 0; j < 4; ++j) {
            int rb = w * 32 + j * 8;
            gload_lds16(Ag + (size_t)rb * DD + ko, Ad + rb * 64);
        }
        #pragma unroll
        for (int j = 0; j < NBI; ++j) {
            int rb = w * BROWS + j * 8;
            gload_lds16(Wg + (size_t)rb * DD + ko, Bd + rb * 64);
        }
    };

    stage(0, 0);
    stage(1, 1);
    if constexpr (BN == 256) asm volatile("s_waitcnt vmcnt(8)" ::: "memory");
    else                     asm volatile("s_waitcnt vmcnt(6)" ::: "memory");
    __builtin_amdgcn_s_barrier();
    __builtin_amdgcn_sched_barrier(0);

    const int swz = lq & 7;
    for (int t = 0; t < NT; ++t) {
        const int buf = t & 1;
        const u16* Ab = AsL + buf * (256 * 64);
        const u16* Bb = BsL + buf * (BN * 64);
        #pragma unroll
        for (int ks = 0; ks < 2; ++ks) {
            short8 af[MR], bf[4];
            #pragma unroll
            for (int m = 0; m < MR; ++m) {
                int arow = wmi * WROW + m * 16 + lq;
                af[m] = *(const short8*)(Ab + arow * 64 + (((ks * 4 + lg) ^ swz) << 3));
            }
            #pragma unroll
            for (int n = 0; n < 4; ++n) {
                int brow = wni * 64 + n * 16 + lq;
                bf[n] = *(const short8*)(Bb + brow * 64 + (((ks * 4 + lg) ^ swz) << 3));
            }
            __builtin_amdgcn_s_setprio(1);
            #pragma unroll
            for (int m = 0; m < MR; ++m)
                #pragma unroll
                for (int n = 0; n < 4; ++n)
                    acc[m][n] = mfma16(af[m], bf[n], acc[m][n]);
            __builtin_amdgcn_s_setprio(0);
        }

        if (t + 1 < NT) {
            __builtin_amdgcn_sched_barrier(0);
            __builtin_amdgcn_s_barrier();
            if (t + 2 < NT) {
                stage(buf, t + 2);
                if constexpr (BN == 256) asm volatile("s_waitcnt vmcnt(8)" ::: "memory");
                else                     asm volatile("s_waitcnt vmcnt(6)" ::: "memory");
            } else {
                asm volatile("s_waitcnt vmcnt(0)" ::: "memory");
            }
            __builtin_amdgcn_s_barrier();
            __builtin_amdgcn_sched_barrier(0);
        }
    }

    #pragma unroll
    for (int m = 0; m < MR; ++m) {
        int grow = bm + wmi * WROW + m * 16 + lg * 4;
        #pragma unroll
        for (int n = 0; n < 4; ++n) {
            int col = wni * 64 + n * 16 + lq;
            #pragma unroll
            for (int q = 0; q < 4; ++q) {
                float v = acc[m][n][q];
                if constexpr (OUTMODE == 0) {
                    ((u16*)C0)[(size_t)(grow + q) * 2048 + bn + col] = f2bf(v);
                } else if constexpr (OUTMODE == 2) {
                    ((float*)C0)[(size_t)(grow + q) * 2048 + bn + col] = v;
                } else {
                    int cg = bn + col;
                    if (cg < 512)
                        ((u16*)C0)[(size_t)(grow + q) * 512 + cg] = f2bf(v);
                    else
                        ((u16*)C1)[(size_t)(grow + q) * 512 + (cg - 512)] = f2bf(v);
                }
            }
        }
    }
}

// ---------------------------------------------------------------------------
// Causal attention — EXACT round-13 version (proven 120 us, passed).
// Fold-balanced + XCD-mapped, counted-vmcnt global_load_lds staging.
// ---------------------------------------------------------------------------
__global__ __launch_bounds__(256, 2)
void attn_mfma(const u16* __restrict__ qg,   // [B,NH,T,128] head-major, pre-scaled
               const u16* __restrict__ kg,   // [B,KVH,T,128]
               const u16* __restrict__ vtg,  // [B,KVH,T/64,128,64] key-permuted
               u16* __restrict__ yg)         // [B,T,NH,128]
{
    __shared__ u16 Ks[2][64 * 128];
    __shared__ u16 Vs[2][128 * 64];

    const int tid = threadIdx.x, wid = tid >> 6, l = tid & 63;
    const int lq = l & 31, hi = l >> 5, hi4 = hi << 2;

    const int bid = blockIdx.x;
    const int xcd  = bid & 7;
    const int s    = bid >> 3;
    const int gsub = s >> 5;
    const int hh   = (s >> 3) & 3;
    const int fold = s & 7;
    const int g    = xcd + (gsub << 3);
    const int b = g >> 2, kvh = g & 3;
    const int h = kvh * 4 + hh;

    const u16* kg_bh = kg + (((size_t)g * TT) << 7);
    const u16* vt_bh = vtg + (size_t)g * (TT / 64) * 8192;
    const u16* q_bh  = qg + (((size_t)(b * NH + h) * TT) << 7);

    const int nta = 2 * fold + 2;
    const int NT  = 34;

    const int kro = l >> 4;
    const int kch = l & 15;
    const int vro = l >> 3;
    const int vchs = (l & 7) ^ vro;

    auto stage = [&](int buf, int kt) {
        #pragma unroll
        for (int i = 0; i < 4; ++i) {
            int kr = wid * 16 + i * 4 + kro;
            gload_lds16(kg_bh + (((size_t)(kt * 64 + kr)) << 7) + ((kch ^ (kr & 7)) << 3),
                        &Ks[buf][(wid * 16 + i * 4) << 7]);
            int vr = wid * 32 + i * 8 + vro;
            gload_lds16(vt_bh + (size_t)kt * 8192 + (vr << 6) + (vchs << 3),
                        &Vs[buf][(wid * 32 + i * 8) << 6]);
        }
    };

    stage(0, 0);
    stage(1, 1);
    asm volatile("s_waitcnt vmcnt(8)" ::: "memory");
    __builtin_amdgcn_s_barrier();
    __builtin_amdgcn_sched_barrier(0);

    int step = 0;

    for (int seg = 0; seg < 2; ++seg) {
        const int qblk = seg ? (15 - fold) : fold;
        const int nseg = seg ? (32 - 2 * fold) : nta;
        const int qrow = qblk * 128 + wid * 32 + lq;
        const int diag = (qblk * 128 + wid * 32) >> 6;

        const u16* qptr = q_bh + ((size_t)qrow << 7) + hi * 8;
        short8 qf[8];
        #pragma unroll
        for (int q = 0; q < 8; ++q)
            qf[q] = *(const short8*)(qptr + q * 16);

        f32x16 accO[4];
        #pragma unroll
        for (int d = 0; d < 4; ++d) accO[d] = zero16();
        float m2 = -1e30f, lr = 0.f;

        for (int kt = 0; kt < nseg; ++kt, ++step) {
            const int buf = step & 1;

            if (kt <= diag) {
                // ---- S^T = K·Q (16 MFMA) ----
                const u16* Kc = Ks[buf];
                f32x16 accS0 = zero16(), accS1 = zero16();
                __builtin_amdgcn_s_setprio(1);
                #pragma unroll
                for (int ss = 0; ss < 8; ++ss) {
                    int c = ((2 * ss + hi) ^ (lq & 7)) << 3;
                    short8 kf0 = *(const short8*)(Kc + (lq << 7) + c);
                    accS0 = mfma32(kf0, qf[ss], accS0);
                    short8 kf1 = *(const short8*)(Kc + ((32 + lq) << 7) + c);
                    accS1 = mfma32(kf1, qf[ss], accS1);
                }
                __builtin_amdgcn_s_setprio(0);

                // ---- scores + causal mask (diag tile only) ----
                float p[32];
                if (kt == diag) {
                    #pragma unroll
                    for (int r = 0; r < 16; ++r) {
                        int key0 = kt * 64 + (r & 3) + 8 * (r >> 2) + hi4;
                        p[r]      = (key0      > qrow) ? -INFINITY : accS0[r];
                        p[16 + r] = (key0 + 32 > qrow) ? -INFINITY : accS1[r];
                    }
                } else {
                    #pragma unroll
                    for (int r = 0; r < 16; ++r) { p[r] = accS0[r]; p[16 + r] = accS1[r]; }
                }

                // ---- row max ----
                float t16[16];
                #pragma unroll
                for (int i = 0; i < 16; ++i) t16[i] = fmaxf(p[i], p[i + 16]);
                #pragma unroll
                for (int i = 0; i < 8; ++i) t16[i] = fmaxf(t16[i], t16[i + 8]);
                #pragma unroll
                for (int i = 0; i < 4; ++i) t16[i] = fmaxf(t16[i], t16[i + 4]);
                float pm = fmaxf(fmaxf(t16[0], t16[1]), fmaxf(t16[2], t16[3]));
                pm = fmaxf(pm, __shfl_xor(pm, 32, 64));

                // ---- defer-max ----
                float mn = m2;
                if (!__all(pm - m2 <= 8.0f)) {
                    mn = fmaxf(m2, pm);
                    float al = exp2f(m2 - mn);
                    lr *= al;
                    #pragma unroll
                    for (int d = 0; d < 4; ++d) accO[d] *= al;
                    m2 = mn;
                }

                // ---- exp2 + row sum ----
                #pragma unroll
                for (int r = 0; r < 32; ++r) p[r] = exp2f(p[r] - mn);
                #pragma unroll
                for (int i = 0; i < 16; ++i) t16[i] = p[i] + p[i + 16];
                #pragma unroll
                for (int i = 0; i < 8; ++i) t16[i] += t16[i + 8];
                #pragma unroll
                for (int i = 0; i < 4; ++i) t16[i] += t16[i + 4];
                float rs = (t16[0] + t16[1]) + (t16[2] + t16[3]);
                rs += __shfl_xor(rs, 32, 64);
                lr += rs;

                // ---- P -> bf16 B-fragments via packed cvt (RTNE) ----
                short8 pfrag[4];
                #pragma unroll
                for (int kb = 0; kb < 2; ++kb)
                    #pragma unroll
                    for (int c = 0; c < 2; ++c) {
                        union { u32 u[4]; short8 s8; } f;
                        #pragma unroll
                        for (int j = 0; j < 4; ++j) {
                            __hip_bfloat162 hb = __float22bfloat162_rn(
                                make_float2(p[kb * 16 + 8 * c + 2 * j],
                                            p[kb * 16 + 8 * c + 2 * j + 1]));
                            f.u[j] = *reinterpret_cast<u32*>(&hb);
                        }
                        pfrag[kb * 2 + c] = f.s8;
                    }

                // ---- O^T += V^T · P^T (16 MFMA) ----
                const u16* Vc = Vs[buf];
                #pragma unroll
                for (int d = 0; d < 4; ++d) {
                    const u16* vr8 = Vc + ((d * 32 + lq) << 6);
                    short8 vf0 = *(const short8*)(vr8 + (((0 + hi) ^ (lq & 7)) << 3));
                    short8 vf1 = *(const short8*)(vr8 + (((2 + hi) ^ (lq & 7)) << 3));
                    short8 vf2 = *(const short8*)(vr8 + (((4 + hi) ^ (lq & 7)) << 3));
                    short8 vf3 = *(const short8*)(vr8 + (((6 + hi) ^ (lq & 7)) << 3));
                    __builtin_amdgcn_s_setprio(1);
                    accO[d] = mfma32(vf0, pfrag[0], accO[d]);
                    accO[d] = mfma32(vf1, pfrag[1], accO[d]);
                    accO[d] = mfma32(vf2, pfrag[2], accO[d]);
                    accO[d] = mfma32(vf3, pfrag[3], accO[d]);
                    __builtin_amdgcn_s_setprio(0);
                }
            }

            // ---- pipeline advance (all waves, uniform) ----
            if (step + 1 < NT) {
                __builtin_amdgcn_sched_barrier(0);
                __builtin_amdgcn_s_barrier();
                if (step + 2 < NT) {
                    int tn = step + 2;
                    stage(buf, (tn < nta) ? tn : tn - nta);
                    asm volatile("s_waitcnt vmcnt(8)" ::: "memory");
                } else {
                    asm volatile("s_waitcnt vmcnt(0)" ::: "memory");
                }
                __builtin_amdgcn_s_barrier();
                __builtin_amdgcn_sched_barrier(0);
            }
        }

        // ---- segment epilogue: normalize (lr lane-uniform) and store ----
        float inv = 1.0f / lr;
        u16* yrow = yg + ((size_t)((b * TT + qrow) * NH + h) << 7);
        #pragma unroll
        for (int d = 0; d < 4; ++d)
            #pragma unroll
            for (int r = 0; r < 4; ++r) {
                u16x4 o;
                #pragma unroll
                for (int q = 0; q < 4; ++q) o[q] = f2bf(accO[d][4 * r + q] * inv);
                *(u16x4*)(yrow + d * 32 + 8 * r + hi4) = o;
            }
    }
}

// ---------------------------------------------------------------------------
extern "C" void kernel_launch(void* const* d_in, const int* in_sizes, int n_in,
                              void* d_out, int out_size, void* d_ws, size_t ws_size,
                              hipStream_t stream)
{
    const float* x      = (const float*)d_in[0];
    const float* q_w    = (const float*)d_in[1];
    const float* k_w    = (const float*)d_in[2];
    const float* v_w    = (const float*)d_in[3];
    const float* out_w  = (const float*)d_in[4];
    const float* q_gain = (const float*)d_in[5];
    float* out = (float*)d_out;

    char* ws = (char*)d_ws;
    u16* qh   = (u16*)(ws);                       // [0,32M)   proj-Q; later y
    u16* xh   = (u16*)(ws + 33554432ull);         // [32,64M)  x bf16; later q2
    u16* wqkv = (u16*)(ws + 67108864ull);         // [64,76.6M) wq+wkv; later kk
    u16* kh   = (u16*)(ws + 79691776ull);         // [76.6..84.6M) K proj; later vtb
    u16* vbh  = (u16*)(ws + 88080384ull);         // [84.6..92.6M) V proj; later wout
    float* cs = (float*)(ws + 96468992ull);       // 0.5MB
    float* sn = cs + TT * 64;                     // 0.5MB (total 97,517,568)
    u16* wq   = wqkv;                             // 8MB  [2048,2048]
    u16* wkv  = wqkv + 4194304;                   // 4MB  [1024,2048] = [k_w; v_w]
    u16* q2   = xh;                               // [B,NH,T,128]
    u16* kk   = wqkv;                             // [B,KVH,T,128]
    u16* vtb  = kh;                               // [B,KVH,T/64,128,64]
    u16* wout = vbh;                              // out-proj weights bf16
    u16* y    = qh;                               // attn output

    dim3 blk(256);

    // fused: x/q_w/k_w/v_w casts + rope tables (NTK base scaling)
    double base = 10000.0 * pow((double)TT / 1024.0, 128.0 / 126.0);
    prep_all<<<dim3(23040), blk, 0, stream>>>(x, q_w, k_w, v_w, xh, wq, wkv,
                                              cs, sn, (float)base);

    // projections (counted-vmcnt 256-tile GEMMs; 256 blocks = 1/CU each)
    gemm256<256, 0><<<dim3(256), dim3(512), 0, stream>>>(xh, wq, qh, nullptr);
    gemm256<128, 1><<<dim3(256), dim3(512), 0, stream>>>(xh, wkv, kh, vbh);

    // fused rmsnorm+rope for Q (gain*scale*log2e folded) and K, head-major
    const float pre_q = 0.08838834764831845f * 1.4426950408889634f;
    rmsrope_qk<<<dim3(40960), blk, 0, stream>>>(qh, q2, kh, kk, cs, sn, q_gain, pre_q);

    // V -> [B,KVH,T/64,128,64] (vtb aliases kh; kh dead after rmsrope_qk)
    transpose_v<<<dim3(TT / 64, 2, BB * NKV), blk, 0, stream>>>(vbh, vtb);

    // out-proj weights (wout aliases vbh; vbh dead after transpose_v)
    cast_f2b<<<dim3(4096), blk, 0, stream>>>(out_w, wout, DD * DD);

    // attention -> y (qh region; proj-Q dead after rmsrope). Grid 512 uniform.
    attn_mfma<<<dim3(512), blk, 0, stream>>>(q2, kk, vtb, y);

    // output projection (fp32 out)
    gemm256<256, 2><<<dim3(256), dim3(512), 0, stream>>>(y, wout, out, nullptr);
}